// Round 9
// baseline (52.461 us; speedup 1.0000x reference)
//
#include <hip/hip_runtime.h>

typedef _Float16 f16x8 __attribute__((ext_vector_type(8)));
typedef float f32x4 __attribute__((ext_vector_type(4)));
typedef unsigned int u32x2 __attribute__((ext_vector_type(2)));

#define MROWS 65536
#define BM 32             // rows per block (shared by 2 column-waves)
#define NBLK (MROWS / BM) // 2048

// ---- d_ws byte offsets ----
#define B1F_OFF 0u       // GEMM1 B frags: [2kt][16nt][64lane][8] f16 = 32768 B (K=64)
#define B2F_OFF 65536u   // GEMM2 B frags: [8kt][16nt][64lane][8] f16 = 131072 B
#define TP_OFF 196608u   // phone_table @ W1[64:192]: [100][256] f32
#define TM_OFF 299008u   // midi_table @ W1[192:256]: [128][256] f32
#define BC_OFF 430080u   // fused bias: [256] f32
#define WFD_OFF 431104u  // fused f0/dur weights: [64][256] f32 (ends 496640)

// Fragment k-slot mapping (all A and B fragments):
//   k = kt*32 + 4*(lane>>4) + (e&3) + 16*(e>>2)
// B fragments use a PERMUTED column layout: tile nt, lane c holds logical
// column (nt>>2)*64 + c*4 + (nt&3).  Wave wc owns nt = wc*8 + j (j=0..7), i.e.
// logical cols [wc*128, wc*128+128): per lane, 8 values = 2 float4 groups at
// g = wc*2 + gl.  Table reads, LN params, bias, output stores stay float4;
// the LN->GEMM2 repack is a per-lane 8B write into the block-shared P buffer.
// C/D: col_tile = lane&15 (permuted); row = (lane>>4)*4 + reg.
// P granule: X = (kt*2+i)*64 + (row&15) + 16*(c&3), half = 8*((c>>2)&1),
// kt = 2*g + (c>>3)  [verified rounds 5-8].

// P-buffer swizzle: XOR addr bits [4:5] with X bits [4:5]; pack writes spread
// across banks, b128 frag reads stay clean (measured: 262K conflicts, benign).
__device__ __forceinline__ unsigned a2off(unsigned X) {
  return (X * 16u) ^ (X & 0x30u);
}

__global__ __launch_bounds__(256) void prep_tables(
    const float* __restrict__ f0_w2, const float* __restrict__ f0_b2,
    const float* __restrict__ ptab, const float* __restrict__ mtab,
    const float* __restrict__ dur_w2, const float* __restrict__ dur_b2,
    const float* __restrict__ W1, const float* __restrict__ pb1,
    float* __restrict__ wsf) {
  const int r = blockIdx.x, n = threadIdx.x;
  if (r < 64) {  // Wfd row r
    float s = 0.f;
    if (r < 32) {
      for (int j = 0; j < 64; ++j) s = fmaf(f0_w2[r * 64 + j], W1[j * 256 + n], s);
    } else {
      for (int j = 0; j < 64; ++j) s = fmaf(dur_w2[(r - 32) * 64 + j], W1[(256 + j) * 256 + n], s);
    }
    wsf[WFD_OFF / 4 + r * 256 + n] = s;
  } else if (r < 164) {  // Tp row
    const int p = r - 64;
    float s = 0.f;
    for (int j = 0; j < 128; ++j) s = fmaf(ptab[p * 128 + j], W1[(64 + j) * 256 + n], s);
    wsf[TP_OFF / 4 + p * 256 + n] = s;
  } else if (r < 292) {  // Tm row
    const int m = r - 164;
    float s = 0.f;
    for (int j = 0; j < 64; ++j) s = fmaf(mtab[m * 64 + j], W1[(192 + j) * 256 + n], s);
    wsf[TM_OFF / 4 + m * 256 + n] = s;
  } else {  // fused bias
    float s = pb1[n];
    for (int j = 0; j < 64; ++j) {
      s = fmaf(f0_b2[j], W1[j * 256 + n], s);
      s = fmaf(dur_b2[j], W1[(256 + j) * 256 + n], s);
    }
    wsf[BC_OFF / 4 + n] = s;
  }
}

__global__ __launch_bounds__(64) void prep_frags(const float* __restrict__ W2, char* __restrict__ ws) {
  const float* Wfd = (const float*)(ws + WFD_OFF);
  const int t = blockIdx.x;
  const int l = threadIdx.x;
  const int qq = l >> 4, c = l & 15;
  if (t < 32) {  // B1: K=64
    const int kt = t >> 4, nt = t & 15;
    const int col = (nt >> 2) * 64 + c * 4 + (nt & 3);  // permuted column layout
    f16x8 v;
#pragma unroll
    for (int e = 0; e < 8; ++e) {
      const int k = kt * 32 + 4 * qq + (e & 3) + 16 * (e >> 2);
      v[e] = (_Float16)Wfd[k * 256 + col];
    }
    *(f16x8*)(ws + B1F_OFF + (unsigned)((kt * 16 + nt) * 64 + l) * 16u) = v;
  } else {  // B2 = proj_w2
    const int t2 = t - 32;
    const int kt = t2 >> 4, nt = t2 & 15;
    const int col = (nt >> 2) * 64 + c * 4 + (nt & 3);  // permuted column layout
    f16x8 v;
#pragma unroll
    for (int e = 0; e < 8; ++e) {
      const int k = kt * 32 + 4 * qq + (e & 3) + 16 * (e >> 2);
      v[e] = (_Float16)W2[k * 256 + col];
    }
    *(f16x8*)(ws + B2F_OFF + (unsigned)((kt * 16 + nt) * 64 + l) * 16u) = v;
  }
}

// Main kernel: 2 waves / 32 shared rows; wave wc owns 128 columns end-to-end.
// 4096 waves total = 4 waves/SIMD. Two barriers on a 2-wave block.
__global__ __launch_bounds__(128, 4) void cond_enc_main(
    const float* __restrict__ f0g, const int* __restrict__ phone,
    const float* __restrict__ durg, const int* __restrict__ midi,
    const float* __restrict__ f0_w1, const float* __restrict__ f0_b1,
    const float* __restrict__ dur_w1, const float* __restrict__ dur_b1,
    const float* __restrict__ ln_g, const float* __restrict__ ln_b,
    const float* __restrict__ pb2, const char* __restrict__ ws,
    float* __restrict__ out) {
  // LDS: P buffer (16 frags x 1KB, swizzled) + LN partials [32][2wc][2]
  __shared__ __align__(16) unsigned char smem[16384 + 512];
  unsigned char* Pbuf = smem;
  float* partials = (float*)(smem + 16384);

  const int tid = threadIdx.x;
  const int l = tid & 63;
  const int wc = tid >> 6;  // 0..1: column half
  const int q = l >> 4;     // 0..3
  const int c = l & 15;     // 0..15
  const int rowbase = blockIdx.x * BM;

  const float* Tp = (const float*)(ws + TP_OFF);
  const float* Tm = (const float*)(ws + TM_OFF);

  // one coalesced load per lane (lane l&31 covers row rowbase + (l&31))
  const int rl = l & 31;
  const float xf_all = f0g[rowbase + rl];
  const float xd_all = durg[rowbase + rl];
  const int ph_all = phone[rowbase + rl];
  const int md_all = midi[rowbase + rl];

  // ---- A1 fragments in registers (K=64: kt0 = f0 MLP, kt1 = dur MLP) ----
  f16x8 a1[2][2];  // [i M-tile][kt]
#pragma unroll
  for (int i = 0; i < 2; ++i) {
    const float xf = __shfl(xf_all, i * 16 + c);
    const float xd = __shfl(xd_all, i * 16 + c);
#pragma unroll
    for (int kh = 0; kh < 2; ++kh) {
      f16x8 v;
#pragma unroll
      for (int e = 0; e < 8; ++e) {
        const int ki = 4 * q + (e & 3) + 16 * (e >> 2);  // 0..31
        const float wv = kh ? dur_w1[ki] : f0_w1[ki];
        const float bv = kh ? dur_b1[ki] : f0_b1[ki];
        const float x = kh ? xd : xf;
        v[e] = (_Float16)fmaxf(fmaf(x, wv, bv), 0.f);
      }
      a1[i][kh] = v;
    }
  }

  // ---- GEMM1 (K=64): acc[i][j], j spans this wave's 8 col-tiles ----
  const f32x4 zero4 = {0.f, 0.f, 0.f, 0.f};
  f32x4 acc[2][8];
#pragma unroll
  for (int i = 0; i < 2; ++i)
#pragma unroll
    for (int j = 0; j < 8; ++j) acc[i][j] = zero4;
  {
    const f16x8* B1p = (const f16x8*)(ws + B1F_OFF);
#pragma unroll
    for (int kt = 0; kt < 2; ++kt) {
      f16x8 bfr[8];
#pragma unroll
      for (int j = 0; j < 8; ++j) bfr[j] = B1p[(kt * 16 + wc * 8 + j) * 64 + l];
#pragma unroll
      for (int i = 0; i < 2; ++i)
#pragma unroll
        for (int j = 0; j < 8; ++j)
          acc[i][j] = __builtin_amdgcn_mfma_f32_16x16x32_f16(a1[i][kt], bfr[j], acc[i][j], 0, 0, 0);
    }
  }

  // ---- epilogue: += bias + Tp[phone] + Tm[midi]; half-row LN partials ----
  const float* bcp = (const float*)(ws + BC_OFF);
  f32x4 bc4[2], g4[2], lb4[2];
#pragma unroll
  for (int gl = 0; gl < 2; ++gl) {
    const int g = wc * 2 + gl;
    bc4[gl] = *(const f32x4*)(bcp + g * 64 + c * 4);
    g4[gl] = *(const f32x4*)(ln_g + g * 64 + c * 4);
    lb4[gl] = *(const f32x4*)(ln_b + g * 64 + c * 4);
  }
#pragma unroll
  for (int i = 0; i < 2; ++i) {
#pragma unroll
    for (int r = 0; r < 4; ++r) {
      const int rrel = i * 16 + q * 4 + r;
      const int ph = __shfl(ph_all, rrel);
      const int md = __shfl(md_all, rrel);
      f32x4 tp4[2], tm4[2];
#pragma unroll
      for (int gl = 0; gl < 2; ++gl) {
        const int g = wc * 2 + gl;
        tp4[gl] = *(const f32x4*)(Tp + ph * 256 + g * 64 + c * 4);
        tm4[gl] = *(const f32x4*)(Tm + md * 256 + g * 64 + c * 4);
      }
      float s = 0.f, ss = 0.f;
#pragma unroll
      for (int j = 0; j < 8; ++j) {
        const int gl = j >> 2, bq = j & 3;
        float v = acc[i][j][r] + bc4[gl][bq] + tp4[gl][bq] + tm4[gl][bq];
        acc[i][j][r] = v;
        s += v;
        ss = fmaf(v, v, ss);
      }
#pragma unroll
      for (int m = 1; m < 16; m <<= 1) {  // reduce this wave's 128-col half
        s += __shfl_xor(s, m, 64);
        ss += __shfl_xor(ss, m, 64);
      }
      if (c == 0) {
        partials[rrel * 4 + wc * 2 + 0] = s;
        partials[rrel * 4 + wc * 2 + 1] = ss;
      }
    }
  }
  __syncthreads();

  // ---- LN (per lane, both halves' partials) + ReLU + pack into shared P ----
  const int lp_base = 16 * (c & 3);
  const unsigned hoff = (unsigned)((c >> 2) & 1) * 8u;
#pragma unroll
  for (int i = 0; i < 2; ++i) {
#pragma unroll
    for (int r = 0; r < 4; ++r) {
      const int rrel = i * 16 + q * 4 + r;
      const f32x4 pr = *(const f32x4*)(partials + rrel * 4);
      const float s = pr[0] + pr[2];
      const float ss = pr[1] + pr[3];
      const float mu = s * (1.f / 256.f);
      const float var = fmaxf(ss * (1.f / 256.f) - mu * mu, 0.f);
      const float rstd = rsqrtf(var + 1e-5f);
#pragma unroll
      for (int gl = 0; gl < 2; ++gl) {
        const int g = wc * 2 + gl;
        unsigned short hw[4];
#pragma unroll
        for (int bq = 0; bq < 4; ++bq) {
          float v = fmaf((acc[i][4 * gl + bq][r] - mu) * rstd, g4[gl][bq], lb4[gl][bq]);
          v = fmaxf(v, 0.f);
          hw[bq] = __builtin_bit_cast(unsigned short, (_Float16)v);
        }
        u32x2 pkt;
        pkt[0] = (unsigned)hw[0] | ((unsigned)hw[1] << 16);
        pkt[1] = (unsigned)hw[2] | ((unsigned)hw[3] << 16);
        const int kt = 2 * g + (c >> 3);
        const unsigned X = (unsigned)((kt * 2 + i) * 64 + (q * 4 + r + lp_base));
        *(u32x2*)(Pbuf + a2off(X) + hoff) = pkt;
      }
    }
  }
  __syncthreads();

  // ---- GEMM2 (K=256, full P; output = this wave's 128 cols), acc reused ----
#pragma unroll
  for (int i = 0; i < 2; ++i)
#pragma unroll
    for (int j = 0; j < 8; ++j) acc[i][j] = zero4;
  {
    const f16x8* B2p = (const f16x8*)(ws + B2F_OFF);
#pragma unroll
    for (int kt = 0; kt < 8; ++kt) {
      const f16x8 a0 = *(const f16x8*)(Pbuf + a2off((unsigned)((kt * 2 + 0) * 64 + l)));
      const f16x8 a1f = *(const f16x8*)(Pbuf + a2off((unsigned)((kt * 2 + 1) * 64 + l)));
      f16x8 bfr[8];
#pragma unroll
      for (int j = 0; j < 8; ++j) bfr[j] = B2p[(kt * 16 + wc * 8 + j) * 64 + l];
#pragma unroll
      for (int j = 0; j < 8; ++j) {
        acc[0][j] = __builtin_amdgcn_mfma_f32_16x16x32_f16(a0, bfr[j], acc[0][j], 0, 0, 0);
        acc[1][j] = __builtin_amdgcn_mfma_f32_16x16x32_f16(a1f, bfr[j], acc[1][j], 0, 0, 0);
      }
    }
  }

  // ---- store: float4 nt-stores ----
  f32x4 b24[2];
#pragma unroll
  for (int gl = 0; gl < 2; ++gl) b24[gl] = *(const f32x4*)(pb2 + (wc * 2 + gl) * 64 + c * 4);
#pragma unroll
  for (int i = 0; i < 2; ++i)
#pragma unroll
    for (int r = 0; r < 4; ++r) {
      const int grow = rowbase + i * 16 + q * 4 + r;
#pragma unroll
      for (int gl = 0; gl < 2; ++gl) {
        const int g = wc * 2 + gl;
        f32x4 st;
#pragma unroll
        for (int bq = 0; bq < 4; ++bq) st[bq] = acc[i][4 * gl + bq][r] + b24[gl][bq];
        __builtin_nontemporal_store(st, (f32x4*)(out + grow * 256 + g * 64 + c * 4));
      }
    }
}

extern "C" void kernel_launch(void* const* d_in, const int* in_sizes, int n_in,
                              void* d_out, int out_size, void* d_ws, size_t ws_size,
                              hipStream_t stream) {
  (void)in_sizes; (void)n_in; (void)out_size; (void)ws_size;
  const float* f0 = (const float*)d_in[0];
  const int* phone = (const int*)d_in[1];
  const float* dur = (const float*)d_in[2];
  const int* midi = (const int*)d_in[3];
  const float* f0_w1 = (const float*)d_in[4];
  const float* f0_b1 = (const float*)d_in[5];
  const float* f0_w2 = (const float*)d_in[6];
  const float* f0_b2 = (const float*)d_in[7];
  const float* ptab = (const float*)d_in[8];
  const float* mtab = (const float*)d_in[9];
  const float* dur_w1 = (const float*)d_in[10];
  const float* dur_b1 = (const float*)d_in[11];
  const float* dur_w2 = (const float*)d_in[12];
  const float* dur_b2 = (const float*)d_in[13];
  const float* W1 = (const float*)d_in[14];
  const float* pb1 = (const float*)d_in[15];
  const float* ln_g = (const float*)d_in[16];
  const float* ln_b = (const float*)d_in[17];
  const float* W2 = (const float*)d_in[18];
  const float* pb2 = (const float*)d_in[19];
  char* ws = (char*)d_ws;
  float* out = (float*)d_out;

  prep_tables<<<293, 256, 0, stream>>>(f0_w2, f0_b2, ptab, mtab, dur_w2, dur_b2, W1, pb1, (float*)ws);
  prep_frags<<<160, 64, 0, stream>>>(W2, ws);
  cond_enc_main<<<NBLK, 128, 0, stream>>>(f0, phone, dur, midi, f0_w1, f0_b1, dur_w1, dur_b1,
                                          ln_g, ln_b, pb2, ws, out);
}

// Round 10
// 51.920 us; speedup vs baseline: 1.0104x; 1.0104x over previous
//
#include <hip/hip_runtime.h>

typedef _Float16 f16x8 __attribute__((ext_vector_type(8)));
typedef float f32x4 __attribute__((ext_vector_type(4)));
typedef unsigned int u32x2 __attribute__((ext_vector_type(2)));

#define MROWS 65536
#define BM 32             // rows per block (shared by 2 column-waves)
#define NBLK (MROWS / BM) // 2048

// ---- d_ws byte offsets ----
#define B1F_OFF 0u       // GEMM1 B frags: [2kt][16nt][64lane][8] f16 = 32768 B (K=64)
#define B2F_OFF 65536u   // GEMM2 B frags: [8kt][16nt][64lane][8] f16 = 131072 B
#define TP_OFF 196608u   // phone_table @ W1[64:192]: [100][256] f32
#define TM_OFF 299008u   // midi_table @ W1[192:256]: [128][256] f32
#define BC_OFF 430080u   // fused bias: [256] f32
#define WFD_OFF 431104u  // fused f0/dur weights: [64][256] f32 (ends 496640)

// Fragment k-slot mapping (all A and B fragments):
//   k = kt*32 + 4*(lane>>4) + (e&3) + 16*(e>>2)
// B fragments use a PERMUTED column layout: tile nt, lane c holds logical
// column (nt>>2)*64 + c*4 + (nt&3).  Wave wc owns nt = wc*8 + j (j=0..7):
// logical cols [wc*128, wc*128+128).  Table reads, LN params, bias, output
// stores are plain float4; the LN->GEMM2 repack is a per-lane 8B write into
// the block-shared P buffer.
// C/D: col_tile = lane&15 (permuted); row = (lane>>4)*4 + reg.
// P granule: X = (kt*2+i)*64 + (row&15) + 16*(c&3), half = 8*((c>>2)&1),
// kt = 2*g + (c>>3)  [verified rounds 5-9].
//
// REGISTER BUDGET (round-9 lesson): __launch_bounds__(128,4) = 128-reg total
// cap (4 waves/EU). Body must fit or the allocator spills to scratch
// (signature: FETCH +21MB, WRITE +43MB, dur 34->57us). This version chunks
// B-frag loads (4 tiles) and table gathers (per-64col group) so peak live
// regs ~= 64 acc + 16 a1 + 16 bfr + ~15 misc < 128.

// P-buffer swizzle: XOR addr bits [4:5] with X bits [4:5].
__device__ __forceinline__ unsigned a2off(unsigned X) {
  return (X * 16u) ^ (X & 0x30u);
}

__global__ __launch_bounds__(256) void prep_tables(
    const float* __restrict__ f0_w2, const float* __restrict__ f0_b2,
    const float* __restrict__ ptab, const float* __restrict__ mtab,
    const float* __restrict__ dur_w2, const float* __restrict__ dur_b2,
    const float* __restrict__ W1, const float* __restrict__ pb1,
    float* __restrict__ wsf) {
  const int r = blockIdx.x, n = threadIdx.x;
  if (r < 64) {  // Wfd row r
    float s = 0.f;
    if (r < 32) {
      for (int j = 0; j < 64; ++j) s = fmaf(f0_w2[r * 64 + j], W1[j * 256 + n], s);
    } else {
      for (int j = 0; j < 64; ++j) s = fmaf(dur_w2[(r - 32) * 64 + j], W1[(256 + j) * 256 + n], s);
    }
    wsf[WFD_OFF / 4 + r * 256 + n] = s;
  } else if (r < 164) {  // Tp row
    const int p = r - 64;
    float s = 0.f;
    for (int j = 0; j < 128; ++j) s = fmaf(ptab[p * 128 + j], W1[(64 + j) * 256 + n], s);
    wsf[TP_OFF / 4 + p * 256 + n] = s;
  } else if (r < 292) {  // Tm row
    const int m = r - 164;
    float s = 0.f;
    for (int j = 0; j < 64; ++j) s = fmaf(mtab[m * 64 + j], W1[(192 + j) * 256 + n], s);
    wsf[TM_OFF / 4 + m * 256 + n] = s;
  } else {  // fused bias
    float s = pb1[n];
    for (int j = 0; j < 64; ++j) {
      s = fmaf(f0_b2[j], W1[j * 256 + n], s);
      s = fmaf(dur_b2[j], W1[(256 + j) * 256 + n], s);
    }
    wsf[BC_OFF / 4 + n] = s;
  }
}

__global__ __launch_bounds__(64) void prep_frags(const float* __restrict__ W2, char* __restrict__ ws) {
  const float* Wfd = (const float*)(ws + WFD_OFF);
  const int t = blockIdx.x;
  const int l = threadIdx.x;
  const int qq = l >> 4, c = l & 15;
  if (t < 32) {  // B1: K=64
    const int kt = t >> 4, nt = t & 15;
    const int col = (nt >> 2) * 64 + c * 4 + (nt & 3);  // permuted column layout
    f16x8 v;
#pragma unroll
    for (int e = 0; e < 8; ++e) {
      const int k = kt * 32 + 4 * qq + (e & 3) + 16 * (e >> 2);
      v[e] = (_Float16)Wfd[k * 256 + col];
    }
    *(f16x8*)(ws + B1F_OFF + (unsigned)((kt * 16 + nt) * 64 + l) * 16u) = v;
  } else {  // B2 = proj_w2
    const int t2 = t - 32;
    const int kt = t2 >> 4, nt = t2 & 15;
    const int col = (nt >> 2) * 64 + c * 4 + (nt & 3);  // permuted column layout
    f16x8 v;
#pragma unroll
    for (int e = 0; e < 8; ++e) {
      const int k = kt * 32 + 4 * qq + (e & 3) + 16 * (e >> 2);
      v[e] = (_Float16)W2[k * 256 + col];
    }
    *(f16x8*)(ws + B2F_OFF + (unsigned)((kt * 16 + nt) * 64 + l) * 16u) = v;
  }
}

// Main kernel: 2 waves / 32 shared rows; wave wc owns 128 columns end-to-end.
// 4096 waves total -> 4 waves/SIMD when the 128-reg budget holds.
__global__ __launch_bounds__(128, 4) void cond_enc_main(
    const float* __restrict__ f0g, const int* __restrict__ phone,
    const float* __restrict__ durg, const int* __restrict__ midi,
    const float* __restrict__ f0_w1, const float* __restrict__ f0_b1,
    const float* __restrict__ dur_w1, const float* __restrict__ dur_b1,
    const float* __restrict__ ln_g, const float* __restrict__ ln_b,
    const float* __restrict__ pb2, const char* __restrict__ ws,
    float* __restrict__ out) {
  // LDS: P buffer (16 frags x 1KB, swizzled) + LN partials [32][2wc][2]
  __shared__ __align__(16) unsigned char smem[16384 + 512];
  unsigned char* Pbuf = smem;
  float* partials = (float*)(smem + 16384);

  const int tid = threadIdx.x;
  const int l = tid & 63;
  const int wc = tid >> 6;  // 0..1: column half
  const int q = l >> 4;     // 0..3
  const int c = l & 15;     // 0..15
  const int rowbase = blockIdx.x * BM;

  const float* Tp = (const float*)(ws + TP_OFF);
  const float* Tm = (const float*)(ws + TM_OFF);

  // one coalesced load per lane (lane l&31 covers row rowbase + (l&31))
  const int rl = l & 31;
  const float xf_all = f0g[rowbase + rl];
  const float xd_all = durg[rowbase + rl];
  const int ph_all = phone[rowbase + rl];
  const int md_all = midi[rowbase + rl];

  // ---- A1 fragments in registers (K=64: kt0 = f0 MLP, kt1 = dur MLP) ----
  f16x8 a1[2][2];  // [i M-tile][kt] = 16 regs
#pragma unroll
  for (int i = 0; i < 2; ++i) {
    const float xf = __shfl(xf_all, i * 16 + c);
    const float xd = __shfl(xd_all, i * 16 + c);
#pragma unroll
    for (int kh = 0; kh < 2; ++kh) {
      f16x8 v;
#pragma unroll
      for (int e = 0; e < 8; ++e) {
        const int ki = 4 * q + (e & 3) + 16 * (e >> 2);  // 0..31
        const float wv = kh ? dur_w1[ki] : f0_w1[ki];
        const float bv = kh ? dur_b1[ki] : f0_b1[ki];
        const float x = kh ? xd : xf;
        v[e] = (_Float16)fmaxf(fmaf(x, wv, bv), 0.f);
      }
      a1[i][kh] = v;
    }
  }

  // ---- GEMM1 (K=64): acc[i][j], j spans this wave's 8 col-tiles ----
  const f32x4 zero4 = {0.f, 0.f, 0.f, 0.f};
  f32x4 acc[2][8];  // 64 regs
#pragma unroll
  for (int i = 0; i < 2; ++i)
#pragma unroll
    for (int j = 0; j < 8; ++j) acc[i][j] = zero4;
  {
    const f16x8* B1p = (const f16x8*)(ws + B1F_OFF);
#pragma unroll
    for (int kt = 0; kt < 2; ++kt) {
#pragma unroll
      for (int jc = 0; jc < 2; ++jc) {  // 4-tile chunks: 16 regs in flight
        f16x8 bfr[4];
#pragma unroll
        for (int j = 0; j < 4; ++j) bfr[j] = B1p[(kt * 16 + wc * 8 + jc * 4 + j) * 64 + l];
#pragma unroll
        for (int i = 0; i < 2; ++i)
#pragma unroll
          for (int j = 0; j < 4; ++j)
            acc[i][jc * 4 + j] =
                __builtin_amdgcn_mfma_f32_16x16x32_f16(a1[i][kt], bfr[j], acc[i][jc * 4 + j], 0, 0, 0);
      }
    }
  }

  // ---- epilogue: += bias + Tp[phone] + Tm[midi]; half-row LN partials ----
  const float* bcp = (const float*)(ws + BC_OFF);
#pragma unroll
  for (int i = 0; i < 2; ++i) {
#pragma unroll
    for (int r = 0; r < 4; ++r) {
      const int rrel = i * 16 + q * 4 + r;
      const int ph = __shfl(ph_all, rrel);
      const int md = __shfl(md_all, rrel);
      float s = 0.f, ss = 0.f;
#pragma unroll
      for (int gl = 0; gl < 2; ++gl) {  // per 64-col group: 3 f32x4 live
        const int g = wc * 2 + gl;
        const f32x4 tp4 = *(const f32x4*)(Tp + ph * 256 + g * 64 + c * 4);
        const f32x4 tm4 = *(const f32x4*)(Tm + md * 256 + g * 64 + c * 4);
        const f32x4 bc4 = *(const f32x4*)(bcp + g * 64 + c * 4);
#pragma unroll
        for (int bq = 0; bq < 4; ++bq) {
          float v = acc[i][4 * gl + bq][r] + bc4[bq] + tp4[bq] + tm4[bq];
          acc[i][4 * gl + bq][r] = v;
          s += v;
          ss = fmaf(v, v, ss);
        }
      }
#pragma unroll
      for (int m = 1; m < 16; m <<= 1) {  // reduce this wave's 128-col half
        s += __shfl_xor(s, m, 64);
        ss += __shfl_xor(ss, m, 64);
      }
      if (c == 0) {
        partials[rrel * 4 + wc * 2 + 0] = s;
        partials[rrel * 4 + wc * 2 + 1] = ss;
      }
    }
  }
  __syncthreads();

  // ---- LN (per lane, both halves' partials) + ReLU + pack into shared P ----
  const int lp_base = 16 * (c & 3);
  const unsigned hoff = (unsigned)((c >> 2) & 1) * 8u;
#pragma unroll
  for (int i = 0; i < 2; ++i) {
#pragma unroll
    for (int r = 0; r < 4; ++r) {
      const int rrel = i * 16 + q * 4 + r;
      const f32x4 pr = *(const f32x4*)(partials + rrel * 4);
      const float s = pr[0] + pr[2];
      const float ss = pr[1] + pr[3];
      const float mu = s * (1.f / 256.f);
      const float var = fmaxf(ss * (1.f / 256.f) - mu * mu, 0.f);
      const float rstd = rsqrtf(var + 1e-5f);
#pragma unroll
      for (int gl = 0; gl < 2; ++gl) {
        const int g = wc * 2 + gl;
        const f32x4 g4 = *(const f32x4*)(ln_g + g * 64 + c * 4);
        const f32x4 lb4 = *(const f32x4*)(ln_b + g * 64 + c * 4);
        unsigned short hw[4];
#pragma unroll
        for (int bq = 0; bq < 4; ++bq) {
          float v = fmaf((acc[i][4 * gl + bq][r] - mu) * rstd, g4[bq], lb4[bq]);
          v = fmaxf(v, 0.f);
          hw[bq] = __builtin_bit_cast(unsigned short, (_Float16)v);
        }
        u32x2 pkt;
        pkt[0] = (unsigned)hw[0] | ((unsigned)hw[1] << 16);
        pkt[1] = (unsigned)hw[2] | ((unsigned)hw[3] << 16);
        const int kt = 2 * g + (c >> 3);
        const unsigned X = (unsigned)((kt * 2 + i) * 64 + (q * 4 + r + lp_base));
        *(u32x2*)(Pbuf + a2off(X) + hoff) = pkt;
      }
    }
  }
  __syncthreads();

  // ---- GEMM2 (K=256, full P; output = this wave's 128 cols), acc reused ----
#pragma unroll
  for (int i = 0; i < 2; ++i)
#pragma unroll
    for (int j = 0; j < 8; ++j) acc[i][j] = zero4;
  {
    const f16x8* B2p = (const f16x8*)(ws + B2F_OFF);
#pragma unroll
    for (int kt = 0; kt < 8; ++kt) {
      const f16x8 a0 = *(const f16x8*)(Pbuf + a2off((unsigned)((kt * 2 + 0) * 64 + l)));
      const f16x8 a1f = *(const f16x8*)(Pbuf + a2off((unsigned)((kt * 2 + 1) * 64 + l)));
#pragma unroll
      for (int jc = 0; jc < 2; ++jc) {  // 4-tile chunks: 16 regs in flight
        f16x8 bfr[4];
#pragma unroll
        for (int j = 0; j < 4; ++j) bfr[j] = B2p[(kt * 16 + wc * 8 + jc * 4 + j) * 64 + l];
#pragma unroll
        for (int j = 0; j < 4; ++j) {
          acc[0][jc * 4 + j] = __builtin_amdgcn_mfma_f32_16x16x32_f16(a0, bfr[j], acc[0][jc * 4 + j], 0, 0, 0);
          acc[1][jc * 4 + j] = __builtin_amdgcn_mfma_f32_16x16x32_f16(a1f, bfr[j], acc[1][jc * 4 + j], 0, 0, 0);
        }
      }
    }
  }

  // ---- store: float4 nt-stores ----
#pragma unroll
  for (int i = 0; i < 2; ++i)
#pragma unroll
    for (int r = 0; r < 4; ++r) {
      const int grow = rowbase + i * 16 + q * 4 + r;
#pragma unroll
      for (int gl = 0; gl < 2; ++gl) {
        const int g = wc * 2 + gl;
        const f32x4 b24 = *(const f32x4*)(pb2 + g * 64 + c * 4);
        f32x4 st;
#pragma unroll
        for (int bq = 0; bq < 4; ++bq) st[bq] = acc[i][4 * gl + bq][r] + b24[bq];
        __builtin_nontemporal_store(st, (f32x4*)(out + grow * 256 + g * 64 + c * 4));
      }
    }
}

extern "C" void kernel_launch(void* const* d_in, const int* in_sizes, int n_in,
                              void* d_out, int out_size, void* d_ws, size_t ws_size,
                              hipStream_t stream) {
  (void)in_sizes; (void)n_in; (void)out_size; (void)ws_size;
  const float* f0 = (const float*)d_in[0];
  const int* phone = (const int*)d_in[1];
  const float* dur = (const float*)d_in[2];
  const int* midi = (const int*)d_in[3];
  const float* f0_w1 = (const float*)d_in[4];
  const float* f0_b1 = (const float*)d_in[5];
  const float* f0_w2 = (const float*)d_in[6];
  const float* f0_b2 = (const float*)d_in[7];
  const float* ptab = (const float*)d_in[8];
  const float* mtab = (const float*)d_in[9];
  const float* dur_w1 = (const float*)d_in[10];
  const float* dur_b1 = (const float*)d_in[11];
  const float* dur_w2 = (const float*)d_in[12];
  const float* dur_b2 = (const float*)d_in[13];
  const float* W1 = (const float*)d_in[14];
  const float* pb1 = (const float*)d_in[15];
  const float* ln_g = (const float*)d_in[16];
  const float* ln_b = (const float*)d_in[17];
  const float* W2 = (const float*)d_in[18];
  const float* pb2 = (const float*)d_in[19];
  char* ws = (char*)d_ws;
  float* out = (float*)d_out;

  prep_tables<<<293, 256, 0, stream>>>(f0_w2, f0_b2, ptab, mtab, dur_w2, dur_b2, W1, pb1, (float*)ws);
  prep_frags<<<160, 64, 0, stream>>>(W2, ws);
  cond_enc_main<<<NBLK, 128, 0, stream>>>(f0, phone, dur, midi, f0_w1, f0_b1, dur_w1, dur_b1,
                                          ln_g, ln_b, pb2, ws, out);
}

// Round 11
// 38.269 us; speedup vs baseline: 1.3709x; 1.3567x over previous
//
#include <hip/hip_runtime.h>

typedef _Float16 f16x8 __attribute__((ext_vector_type(8)));
typedef float f32x4 __attribute__((ext_vector_type(4)));
typedef unsigned int u32x2 __attribute__((ext_vector_type(2)));

#define MROWS 65536
#define BM 32             // rows per block
#define NBLK (MROWS / BM) // 2048

// ---- d_ws byte offsets ----
#define B1F_OFF 0u       // GEMM1 B frags: [2kt][16nt][64lane][8] f16 = 32768 B (K=64)
#define B2F_OFF 65536u   // GEMM2 B frags: [8kt][16nt][64lane][8] f16 = 131072 B
#define TP_OFF 196608u   // phone_table @ W1[64:192]: [100][256] f32
#define TM_OFF 299008u   // midi_table @ W1[192:256]: [128][256] f32
#define BC_OFF 430080u   // fused bias: [256] f32
#define WFD_OFF 431104u  // fused f0/dur weights: [64][256] f32 (ends 496640)

// Fragment k-slot mapping (all A and B fragments):
//   k = kt*32 + 4*(lane>>4) + (e&3) + 16*(e>>2)
// B fragments use a PERMUTED column layout: tile nt, lane c holds logical
// column (nt>>2)*64 + c*4 + (nt&3).
// C/D: col_tile = lane&15 (permuted); row = (lane>>4)*4 + reg.
// P granule: X = (kt*2+i)*64 + (row&15) + 16*(c&3), half = 8*((c>>2)&1),
// kt = 2*g + (c>>3)  [verified rounds 5-10].
//
// REGISTER BUDGET (rounds 9/10 lesson): a 128-reg cap cannot host 64 acc
// regs + body. This version splits work so EACH PHASE needs only 32 acc regs:
//   GEMM1: wave w -> 16 rows ((w&1)) x 128 cols ((w>>1))   acc[8]    = 32
//   GEMM2: wave w -> 32 rows x 64 cols (nt = w*4+j)        acc2[2][4]= 32
// (legal: the pack barrier already decouples the two phases' work splits)
// Peak live ~88 regs < 128 -> __launch_bounds__(256,4) = 4 waves/SIMD.
// Spill signature to watch: FETCH >> 3MB, WRITE >> 66MB.

// P-buffer swizzle: XOR addr bits [4:5] with X bits [4:5].
__device__ __forceinline__ unsigned a2off(unsigned X) {
  return (X * 16u) ^ (X & 0x30u);
}

__global__ __launch_bounds__(256) void prep_tables(
    const float* __restrict__ f0_w2, const float* __restrict__ f0_b2,
    const float* __restrict__ ptab, const float* __restrict__ mtab,
    const float* __restrict__ dur_w2, const float* __restrict__ dur_b2,
    const float* __restrict__ W1, const float* __restrict__ pb1,
    float* __restrict__ wsf) {
  const int r = blockIdx.x, n = threadIdx.x;
  if (r < 64) {  // Wfd row r
    float s = 0.f;
    if (r < 32) {
      for (int j = 0; j < 64; ++j) s = fmaf(f0_w2[r * 64 + j], W1[j * 256 + n], s);
    } else {
      for (int j = 0; j < 64; ++j) s = fmaf(dur_w2[(r - 32) * 64 + j], W1[(256 + j) * 256 + n], s);
    }
    wsf[WFD_OFF / 4 + r * 256 + n] = s;
  } else if (r < 164) {  // Tp row
    const int p = r - 64;
    float s = 0.f;
    for (int j = 0; j < 128; ++j) s = fmaf(ptab[p * 128 + j], W1[(64 + j) * 256 + n], s);
    wsf[TP_OFF / 4 + p * 256 + n] = s;
  } else if (r < 292) {  // Tm row
    const int m = r - 164;
    float s = 0.f;
    for (int j = 0; j < 64; ++j) s = fmaf(mtab[m * 64 + j], W1[(192 + j) * 256 + n], s);
    wsf[TM_OFF / 4 + m * 256 + n] = s;
  } else {  // fused bias
    float s = pb1[n];
    for (int j = 0; j < 64; ++j) {
      s = fmaf(f0_b2[j], W1[j * 256 + n], s);
      s = fmaf(dur_b2[j], W1[(256 + j) * 256 + n], s);
    }
    wsf[BC_OFF / 4 + n] = s;
  }
}

__global__ __launch_bounds__(64) void prep_frags(const float* __restrict__ W2, char* __restrict__ ws) {
  const float* Wfd = (const float*)(ws + WFD_OFF);
  const int t = blockIdx.x;
  const int l = threadIdx.x;
  const int qq = l >> 4, c = l & 15;
  if (t < 32) {  // B1: K=64
    const int kt = t >> 4, nt = t & 15;
    const int col = (nt >> 2) * 64 + c * 4 + (nt & 3);  // permuted column layout
    f16x8 v;
#pragma unroll
    for (int e = 0; e < 8; ++e) {
      const int k = kt * 32 + 4 * qq + (e & 3) + 16 * (e >> 2);
      v[e] = (_Float16)Wfd[k * 256 + col];
    }
    *(f16x8*)(ws + B1F_OFF + (unsigned)((kt * 16 + nt) * 64 + l) * 16u) = v;
  } else {  // B2 = proj_w2
    const int t2 = t - 32;
    const int kt = t2 >> 4, nt = t2 & 15;
    const int col = (nt >> 2) * 64 + c * 4 + (nt & 3);  // permuted column layout
    f16x8 v;
#pragma unroll
    for (int e = 0; e < 8; ++e) {
      const int k = kt * 32 + 4 * qq + (e & 3) + 16 * (e >> 2);
      v[e] = (_Float16)W2[k * 256 + col];
    }
    *(f16x8*)(ws + B2F_OFF + (unsigned)((kt * 16 + nt) * 64 + l) * 16u) = v;
  }
}

// Main kernel: 4 waves, 32 rows/block; phase-dependent work split (see above).
__global__ __launch_bounds__(256, 4) void cond_enc_main(
    const float* __restrict__ f0g, const int* __restrict__ phone,
    const float* __restrict__ durg, const int* __restrict__ midi,
    const float* __restrict__ f0_w1, const float* __restrict__ f0_b1,
    const float* __restrict__ dur_w1, const float* __restrict__ dur_b1,
    const float* __restrict__ ln_g, const float* __restrict__ ln_b,
    const float* __restrict__ pb2, const char* __restrict__ ws,
    float* __restrict__ out) {
  // LDS: P buffer (16 frags x 1KB, swizzled) + LN partials [32][2][2]
  __shared__ __align__(16) unsigned char smem[16384 + 512];
  unsigned char* Pbuf = smem;
  float* partials = (float*)(smem + 16384);

  const int tid = threadIdx.x;
  const int l = tid & 63;
  const int w = tid >> 6;   // wave 0..3
  const int wi = w & 1;     // GEMM1: row half (16 rows)
  const int wh = w >> 1;    // GEMM1: column half (128 cols)
  const int q = l >> 4;     // 0..3
  const int c = l & 15;     // 0..15
  const int rowbase = blockIdx.x * BM;

  const float* Tp = (const float*)(ws + TP_OFF);
  const float* Tm = (const float*)(ws + TM_OFF);

  // one coalesced load per lane (lane l&31 covers block row l&31)
  const int rl = l & 31;
  const float xf_all = f0g[rowbase + rl];
  const float xd_all = durg[rowbase + rl];
  const int ph_all = phone[rowbase + rl];
  const int md_all = midi[rowbase + rl];

  // ---- A1 fragment for this wave's 16 rows (K=64: kt0=f0, kt1=dur) ----
  f16x8 a1[2];  // 8 regs
  {
    const float xf = __shfl(xf_all, wi * 16 + c);
    const float xd = __shfl(xd_all, wi * 16 + c);
#pragma unroll
    for (int kh = 0; kh < 2; ++kh) {
      f16x8 v;
#pragma unroll
      for (int e = 0; e < 8; ++e) {
        const int ki = 4 * q + (e & 3) + 16 * (e >> 2);  // 0..31
        const float wv = kh ? dur_w1[ki] : f0_w1[ki];
        const float bv = kh ? dur_b1[ki] : f0_b1[ki];
        const float x = kh ? xd : xf;
        v[e] = (_Float16)fmaxf(fmaf(x, wv, bv), 0.f);
      }
      a1[kh] = v;
    }
  }

  // ---- GEMM1 (K=64): 16 rows x 128 cols -> acc[8] = 32 regs ----
  const f32x4 zero4 = {0.f, 0.f, 0.f, 0.f};
  f32x4 acc[8];
#pragma unroll
  for (int j = 0; j < 8; ++j) acc[j] = zero4;
  {
    const f16x8* B1p = (const f16x8*)(ws + B1F_OFF);
#pragma unroll
    for (int kt = 0; kt < 2; ++kt) {
#pragma unroll
      for (int jc = 0; jc < 2; ++jc) {  // 4-tile chunks
        f16x8 bfr[4];
#pragma unroll
        for (int j = 0; j < 4; ++j) bfr[j] = B1p[(kt * 16 + wh * 8 + jc * 4 + j) * 64 + l];
#pragma unroll
        for (int j = 0; j < 4; ++j)
          acc[jc * 4 + j] = __builtin_amdgcn_mfma_f32_16x16x32_f16(a1[kt], bfr[j], acc[jc * 4 + j], 0, 0, 0);
      }
    }
  }

  // ---- epilogue: += bias + Tp[phone] + Tm[midi]; LN partials (16 rows x half) ----
  const float* bcp = (const float*)(ws + BC_OFF);
#pragma unroll
  for (int r = 0; r < 4; ++r) {
    const int rrel = wi * 16 + q * 4 + r;  // block-relative row
    const int ph = __shfl(ph_all, rrel);
    const int md = __shfl(md_all, rrel);
    float s = 0.f, ss = 0.f;
#pragma unroll
    for (int gl = 0; gl < 2; ++gl) {
      const int g = wh * 2 + gl;
      const f32x4 tp4 = *(const f32x4*)(Tp + ph * 256 + g * 64 + c * 4);
      const f32x4 tm4 = *(const f32x4*)(Tm + md * 256 + g * 64 + c * 4);
      const f32x4 bc4 = *(const f32x4*)(bcp + g * 64 + c * 4);
#pragma unroll
      for (int bq = 0; bq < 4; ++bq) {
        float v = acc[4 * gl + bq][r] + bc4[bq] + tp4[bq] + tm4[bq];
        acc[4 * gl + bq][r] = v;
        s += v;
        ss = fmaf(v, v, ss);
      }
    }
#pragma unroll
    for (int m = 1; m < 16; m <<= 1) {  // reduce this wave's 128-col half
      s += __shfl_xor(s, m, 64);
      ss += __shfl_xor(ss, m, 64);
    }
    if (c == 0) {
      partials[rrel * 4 + wh * 2 + 0] = s;
      partials[rrel * 4 + wh * 2 + 1] = ss;
    }
  }
  __syncthreads();

  // ---- LN (per lane) + ReLU + pack this wave's quadrant into shared P ----
  const int lp_base = 16 * (c & 3);
  const unsigned hoff = (unsigned)((c >> 2) & 1) * 8u;
#pragma unroll
  for (int r = 0; r < 4; ++r) {
    const int rrel = wi * 16 + q * 4 + r;
    const f32x4 pr = *(const f32x4*)(partials + rrel * 4);
    const float s = pr[0] + pr[2];
    const float ss = pr[1] + pr[3];
    const float mu = s * (1.f / 256.f);
    const float var = fmaxf(ss * (1.f / 256.f) - mu * mu, 0.f);
    const float rstd = rsqrtf(var + 1e-5f);
#pragma unroll
    for (int gl = 0; gl < 2; ++gl) {
      const int g = wh * 2 + gl;
      const f32x4 g4 = *(const f32x4*)(ln_g + g * 64 + c * 4);
      const f32x4 lb4 = *(const f32x4*)(ln_b + g * 64 + c * 4);
      unsigned short hw[4];
#pragma unroll
      for (int bq = 0; bq < 4; ++bq) {
        float v = fmaf((acc[4 * gl + bq][r] - mu) * rstd, g4[bq], lb4[bq]);
        v = fmaxf(v, 0.f);
        hw[bq] = __builtin_bit_cast(unsigned short, (_Float16)v);
      }
      u32x2 pkt;
      pkt[0] = (unsigned)hw[0] | ((unsigned)hw[1] << 16);
      pkt[1] = (unsigned)hw[2] | ((unsigned)hw[3] << 16);
      const int kt = 2 * g + (c >> 3);
      const unsigned X = (unsigned)((kt * 2 + wi) * 64 + (q * 4 + r + lp_base));
      *(u32x2*)(Pbuf + a2off(X) + hoff) = pkt;
    }
  }
  __syncthreads();

  // ---- GEMM2 (K=256): 32 rows x 64 cols (nt = w*4+j) -> acc2[2][4] = 32 regs ----
  f32x4 acc2[2][4];
#pragma unroll
  for (int i = 0; i < 2; ++i)
#pragma unroll
    for (int j = 0; j < 4; ++j) acc2[i][j] = zero4;
  {
    const f16x8* B2p = (const f16x8*)(ws + B2F_OFF);
#pragma unroll
    for (int kt = 0; kt < 8; ++kt) {
      const f16x8 a0 = *(const f16x8*)(Pbuf + a2off((unsigned)((kt * 2 + 0) * 64 + l)));
      const f16x8 a1f = *(const f16x8*)(Pbuf + a2off((unsigned)((kt * 2 + 1) * 64 + l)));
      f16x8 bfr[4];
#pragma unroll
      for (int j = 0; j < 4; ++j) bfr[j] = B2p[(kt * 16 + w * 4 + j) * 64 + l];
#pragma unroll
      for (int j = 0; j < 4; ++j) {
        acc2[0][j] = __builtin_amdgcn_mfma_f32_16x16x32_f16(a0, bfr[j], acc2[0][j], 0, 0, 0);
        acc2[1][j] = __builtin_amdgcn_mfma_f32_16x16x32_f16(a1f, bfr[j], acc2[1][j], 0, 0, 0);
      }
    }
  }

  // ---- store: 32 rows x 64 cols (cols w*64 + c*4 + j), float4 nt-stores ----
  const f32x4 b24 = *(const f32x4*)(pb2 + w * 64 + c * 4);
#pragma unroll
  for (int i = 0; i < 2; ++i)
#pragma unroll
    for (int r = 0; r < 4; ++r) {
      const int grow = rowbase + i * 16 + q * 4 + r;
      f32x4 st;
#pragma unroll
      for (int j = 0; j < 4; ++j) st[j] = acc2[i][j][r] + b24[j];
      __builtin_nontemporal_store(st, (f32x4*)(out + grow * 256 + w * 64 + c * 4));
    }
}

extern "C" void kernel_launch(void* const* d_in, const int* in_sizes, int n_in,
                              void* d_out, int out_size, void* d_ws, size_t ws_size,
                              hipStream_t stream) {
  (void)in_sizes; (void)n_in; (void)out_size; (void)ws_size;
  const float* f0 = (const float*)d_in[0];
  const int* phone = (const int*)d_in[1];
  const float* dur = (const float*)d_in[2];
  const int* midi = (const int*)d_in[3];
  const float* f0_w1 = (const float*)d_in[4];
  const float* f0_b1 = (const float*)d_in[5];
  const float* f0_w2 = (const float*)d_in[6];
  const float* f0_b2 = (const float*)d_in[7];
  const float* ptab = (const float*)d_in[8];
  const float* mtab = (const float*)d_in[9];
  const float* dur_w1 = (const float*)d_in[10];
  const float* dur_b1 = (const float*)d_in[11];
  const float* dur_w2 = (const float*)d_in[12];
  const float* dur_b2 = (const float*)d_in[13];
  const float* W1 = (const float*)d_in[14];
  const float* pb1 = (const float*)d_in[15];
  const float* ln_g = (const float*)d_in[16];
  const float* ln_b = (const float*)d_in[17];
  const float* W2 = (const float*)d_in[18];
  const float* pb2 = (const float*)d_in[19];
  char* ws = (char*)d_ws;
  float* out = (float*)d_out;

  prep_tables<<<293, 256, 0, stream>>>(f0_w2, f0_b2, ptab, mtab, dur_w2, dur_b2, W1, pb1, (float*)ws);
  prep_frags<<<160, 64, 0, stream>>>(W2, ws);
  cond_enc_main<<<NBLK, 256, 0, stream>>>(f0, phone, dur, midi, f0_w1, f0_b1, dur_w1, dur_b1,
                                          ln_g, ln_b, pb2, ws, out);
}

// Round 12
// 37.824 us; speedup vs baseline: 1.3870x; 1.0118x over previous
//
#include <hip/hip_runtime.h>

typedef _Float16 f16x8 __attribute__((ext_vector_type(8)));
typedef float f32x4 __attribute__((ext_vector_type(4)));
typedef unsigned int u32x2 __attribute__((ext_vector_type(2)));

#define MROWS 65536
#define BM 64             // rows per block (4 waves)
#define NBLK (MROWS / BM) // 1024

// ---- d_ws byte offsets ----
#define B1F_OFF 0u       // GEMM1 B frags: [2kt][16nt][64lane][8] f16 = 32768 B (K=64)
#define B2F_OFF 65536u   // GEMM2 B frags: [8kt][16nt][64lane][8] f16 = 131072 B
#define TP_OFF 196608u   // phone_table @ W1[64:192]: [100][256] f32
#define TM_OFF 299008u   // midi_table @ W1[192:256]: [128][256] f32
#define BC_OFF 430080u   // fused bias: [256] f32
#define WFD_OFF 431104u  // fused f0/dur weights: [64][256] f32 (ends 496640)

// Fragment k-slot mapping (all A and B fragments):
//   k = kt*32 + 4*(lane>>4) + (e&3) + 16*(e>>2)
// B fragments use a PERMUTED column layout: tile nt, lane c holds logical
// column (nt>>2)*64 + c*4 + (nt&3).
// C/D: col_tile = lane&15 (permuted); row = (lane>>4)*4 + reg.
// P granule (64-row tile): X = (kt*4 + it)*64 + (row&15) + 16*(c&3),
// byte half = 8*((c>>2)&1), kt = 2*g + (c>>3)   [verified rounds 5-11].
//
// TRAFFIC MODEL (rounds 8/11 post-mortem): main kernel is pinned at ~18-20
// TB/s aggregate L2 read BW, so the lever is bytes, not occupancy.
//   GEMM1: wave = 32 rows x 128 cols  (acc 64 regs)  -> B1  67 MB total
//   GEMM2: wave = 64 rows x  64 cols  (acc 64 regs)  -> B2 134 MB total
// REGISTER BUDGET: __launch_bounds__(256,3) cap ~170; peak live ~120 leaves
// ~50 regs of load-pipeline slack (rounds 9/10: cap128 with ~90 live spilled).
// Spill signature: FETCH >> 3 MB, WRITE >> 66 MB.

// P-buffer swizzle: XOR addr bits [4:5] with X bits [4:5].
__device__ __forceinline__ unsigned a2off(unsigned X) {
  return (X * 16u) ^ (X & 0x30u);
}

// prep_tables with 4-way K-split (1024 thr): 128-deep serial loops were ~5us
// of wall at 293 blocks; split cuts to ~1.5us. Deterministic (fixed order).
__global__ __launch_bounds__(1024) void prep_tables(
    const float* __restrict__ f0_w2, const float* __restrict__ f0_b2,
    const float* __restrict__ ptab, const float* __restrict__ mtab,
    const float* __restrict__ dur_w2, const float* __restrict__ dur_b2,
    const float* __restrict__ W1, const float* __restrict__ pb1,
    float* __restrict__ wsf) {
  __shared__ float red[4][256];
  const int r = blockIdx.x;
  const int n = threadIdx.x & 255;
  const int ks = threadIdx.x >> 8;  // 0..3
  float s = 0.f;
  if (r < 64) {  // Wfd row r: K=64 -> 16/ks
    if (r < 32) {
      for (int j = ks * 16; j < ks * 16 + 16; ++j) s = fmaf(f0_w2[r * 64 + j], W1[j * 256 + n], s);
    } else {
      for (int j = ks * 16; j < ks * 16 + 16; ++j)
        s = fmaf(dur_w2[(r - 32) * 64 + j], W1[(256 + j) * 256 + n], s);
    }
  } else if (r < 164) {  // Tp row: K=128 -> 32/ks
    const int p = r - 64;
    for (int j = ks * 32; j < ks * 32 + 32; ++j) s = fmaf(ptab[p * 128 + j], W1[(64 + j) * 256 + n], s);
  } else if (r < 292) {  // Tm row: K=64 -> 16/ks
    const int m = r - 164;
    for (int j = ks * 16; j < ks * 16 + 16; ++j) s = fmaf(mtab[m * 64 + j], W1[(192 + j) * 256 + n], s);
  } else {  // fused bias: two K=64 loops -> 16/ks each
    for (int j = ks * 16; j < ks * 16 + 16; ++j) {
      s = fmaf(f0_b2[j], W1[j * 256 + n], s);
      s = fmaf(dur_b2[j], W1[(256 + j) * 256 + n], s);
    }
  }
  red[ks][n] = s;
  __syncthreads();
  if (ks == 0) {
    float t = red[0][n] + red[1][n] + red[2][n] + red[3][n];
    if (r < 64) wsf[WFD_OFF / 4 + r * 256 + n] = t;
    else if (r < 164) wsf[TP_OFF / 4 + (r - 64) * 256 + n] = t;
    else if (r < 292) wsf[TM_OFF / 4 + (r - 164) * 256 + n] = t;
    else wsf[BC_OFF / 4 + n] = t + pb1[n];
  }
}

__global__ __launch_bounds__(64) void prep_frags(const float* __restrict__ W2, char* __restrict__ ws) {
  const float* Wfd = (const float*)(ws + WFD_OFF);
  const int t = blockIdx.x;
  const int l = threadIdx.x;
  const int qq = l >> 4, c = l & 15;
  if (t < 32) {  // B1: K=64
    const int kt = t >> 4, nt = t & 15;
    const int col = (nt >> 2) * 64 + c * 4 + (nt & 3);  // permuted column layout
    f16x8 v;
#pragma unroll
    for (int e = 0; e < 8; ++e) {
      const int k = kt * 32 + 4 * qq + (e & 3) + 16 * (e >> 2);
      v[e] = (_Float16)Wfd[k * 256 + col];
    }
    *(f16x8*)(ws + B1F_OFF + (unsigned)((kt * 16 + nt) * 64 + l) * 16u) = v;
  } else {  // B2 = proj_w2
    const int t2 = t - 32;
    const int kt = t2 >> 4, nt = t2 & 15;
    const int col = (nt >> 2) * 64 + c * 4 + (nt & 3);  // permuted column layout
    f16x8 v;
#pragma unroll
    for (int e = 0; e < 8; ++e) {
      const int k = kt * 32 + 4 * qq + (e & 3) + 16 * (e >> 2);
      v[e] = (_Float16)W2[k * 256 + col];
    }
    *(f16x8*)(ws + B2F_OFF + (unsigned)((kt * 16 + nt) * 64 + l) * 16u) = v;
  }
}

// Main kernel: 4 waves, 64 rows/block; phase-dependent work split:
//   GEMM1/epilogue: wave (wi,wh) -> rows wi*32..+32, cols wh*128..+128
//   GEMM2/store:    wave w       -> all 64 rows, cols w*64..+64
__global__ __launch_bounds__(256, 3) void cond_enc_main(
    const float* __restrict__ f0g, const int* __restrict__ phone,
    const float* __restrict__ durg, const int* __restrict__ midi,
    const float* __restrict__ f0_w1, const float* __restrict__ f0_b1,
    const float* __restrict__ dur_w1, const float* __restrict__ dur_b1,
    const float* __restrict__ ln_g, const float* __restrict__ ln_b,
    const float* __restrict__ pb2, const char* __restrict__ ws,
    float* __restrict__ out) {
  // LDS: P buffer (32 frags x 1KB, swizzled) + LN partials [64][4]
  __shared__ __align__(16) unsigned char smem[32768 + 1024];
  unsigned char* Pbuf = smem;
  float* partials = (float*)(smem + 32768);

  const int tid = threadIdx.x;
  const int l = tid & 63;
  const int w = tid >> 6;   // wave 0..3
  const int wi = w & 1;     // GEMM1: row half (32 rows)
  const int wh = w >> 1;    // GEMM1: column half (128 cols)
  const int q = l >> 4;     // 0..3
  const int c = l & 15;     // 0..15
  const int rowbase = blockIdx.x * BM;

  const float* Tp = (const float*)(ws + TP_OFF);
  const float* Tm = (const float*)(ws + TM_OFF);

  // one coalesced load per lane (lane l covers block row l; 4x wave redundancy, L1-hot)
  const float xf_all = f0g[rowbase + l];
  const float xd_all = durg[rowbase + l];
  const int ph_all = phone[rowbase + l];
  const int md_all = midi[rowbase + l];

  // ---- A1 fragments for this wave's 32 rows (K=64: kt0=f0, kt1=dur) ----
  f16x8 a1[2][2];  // [i row-tile][kt] = 16 regs
#pragma unroll
  for (int i = 0; i < 2; ++i) {
    const float xf = __shfl(xf_all, wi * 32 + i * 16 + c);
    const float xd = __shfl(xd_all, wi * 32 + i * 16 + c);
#pragma unroll
    for (int kh = 0; kh < 2; ++kh) {
      f16x8 v;
#pragma unroll
      for (int e = 0; e < 8; ++e) {
        const int ki = 4 * q + (e & 3) + 16 * (e >> 2);  // 0..31
        const float wv = kh ? dur_w1[ki] : f0_w1[ki];
        const float bv = kh ? dur_b1[ki] : f0_b1[ki];
        const float x = kh ? xd : xf;
        v[e] = (_Float16)fmaxf(fmaf(x, wv, bv), 0.f);
      }
      a1[i][kh] = v;
    }
  }

  // ---- GEMM1 (K=64): 32 rows x 128 cols -> acc1[2][8] = 64 regs ----
  const f32x4 zero4 = {0.f, 0.f, 0.f, 0.f};
  f32x4 acc1[2][8];
#pragma unroll
  for (int i = 0; i < 2; ++i)
#pragma unroll
    for (int j = 0; j < 8; ++j) acc1[i][j] = zero4;
  {
    const f16x8* B1p = (const f16x8*)(ws + B1F_OFF);
#pragma unroll
    for (int kt = 0; kt < 2; ++kt) {
#pragma unroll
      for (int jc = 0; jc < 2; ++jc) {  // 4-tile chunks
        f16x8 bfr[4];
#pragma unroll
        for (int j = 0; j < 4; ++j) bfr[j] = B1p[(kt * 16 + wh * 8 + jc * 4 + j) * 64 + l];
#pragma unroll
        for (int i = 0; i < 2; ++i)
#pragma unroll
          for (int j = 0; j < 4; ++j)
            acc1[i][jc * 4 + j] =
                __builtin_amdgcn_mfma_f32_16x16x32_f16(a1[i][kt], bfr[j], acc1[i][jc * 4 + j], 0, 0, 0);
      }
    }
  }

  // ---- epilogue: += bias + Tp[phone] + Tm[midi]; half-row LN partials ----
  const float* bcp = (const float*)(ws + BC_OFF);
#pragma unroll
  for (int i = 0; i < 2; ++i) {
#pragma unroll
    for (int r = 0; r < 4; ++r) {
      const int rrel = wi * 32 + i * 16 + q * 4 + r;  // block-relative row
      const int ph = __shfl(ph_all, rrel);
      const int md = __shfl(md_all, rrel);
      float s = 0.f, ss = 0.f;
#pragma unroll
      for (int gl = 0; gl < 2; ++gl) {
        const int g = wh * 2 + gl;
        const f32x4 tp4 = *(const f32x4*)(Tp + ph * 256 + g * 64 + c * 4);
        const f32x4 tm4 = *(const f32x4*)(Tm + md * 256 + g * 64 + c * 4);
        const f32x4 bc4 = *(const f32x4*)(bcp + g * 64 + c * 4);
#pragma unroll
        for (int bq = 0; bq < 4; ++bq) {
          float v = acc1[i][4 * gl + bq][r] + bc4[bq] + tp4[bq] + tm4[bq];
          acc1[i][4 * gl + bq][r] = v;
          s += v;
          ss = fmaf(v, v, ss);
        }
      }
#pragma unroll
      for (int m = 1; m < 16; m <<= 1) {  // reduce this wave's 128-col half
        s += __shfl_xor(s, m, 64);
        ss += __shfl_xor(ss, m, 64);
      }
      if (c == 0) {
        partials[rrel * 4 + wh * 2 + 0] = s;
        partials[rrel * 4 + wh * 2 + 1] = ss;
      }
    }
  }
  __syncthreads();

  // ---- LN (per lane) + ReLU + pack this wave's quadrant into shared P ----
  const int lp_base = 16 * (c & 3);
  const unsigned hoff = (unsigned)((c >> 2) & 1) * 8u;
#pragma unroll
  for (int i = 0; i < 2; ++i) {
#pragma unroll
    for (int r = 0; r < 4; ++r) {
      const int rrel = wi * 32 + i * 16 + q * 4 + r;
      const int it = wi * 2 + i;  // 16-row tile index 0..3
      const f32x4 pr = *(const f32x4*)(partials + rrel * 4);
      const float s = pr[0] + pr[2];
      const float ss = pr[1] + pr[3];
      const float mu = s * (1.f / 256.f);
      const float var = fmaxf(ss * (1.f / 256.f) - mu * mu, 0.f);
      const float rstd = rsqrtf(var + 1e-5f);
#pragma unroll
      for (int gl = 0; gl < 2; ++gl) {
        const int g = wh * 2 + gl;
        const f32x4 g4 = *(const f32x4*)(ln_g + g * 64 + c * 4);
        const f32x4 lb4 = *(const f32x4*)(ln_b + g * 64 + c * 4);
        unsigned short hw[4];
#pragma unroll
        for (int bq = 0; bq < 4; ++bq) {
          float v = fmaf((acc1[i][4 * gl + bq][r] - mu) * rstd, g4[bq], lb4[bq]);
          v = fmaxf(v, 0.f);
          hw[bq] = __builtin_bit_cast(unsigned short, (_Float16)v);
        }
        u32x2 pkt;
        pkt[0] = (unsigned)hw[0] | ((unsigned)hw[1] << 16);
        pkt[1] = (unsigned)hw[2] | ((unsigned)hw[3] << 16);
        const int kt = 2 * g + (c >> 3);
        const unsigned X = (unsigned)((kt * 4 + it) * 64 + (q * 4 + r + lp_base));
        *(u32x2*)(Pbuf + a2off(X) + hoff) = pkt;
      }
    }
  }
  __syncthreads();

  // ---- GEMM2 (K=256): 64 rows x 64 cols (nt = w*4+j) -> acc2[4][4] = 64 regs ----
  f32x4 acc2[4][4];
#pragma unroll
  for (int it = 0; it < 4; ++it)
#pragma unroll
    for (int j = 0; j < 4; ++j) acc2[it][j] = zero4;
  {
    const f16x8* B2p = (const f16x8*)(ws + B2F_OFF);
#pragma unroll
    for (int kt = 0; kt < 8; ++kt) {
      f16x8 av[4], bfr[4];
#pragma unroll
      for (int it = 0; it < 4; ++it)
        av[it] = *(const f16x8*)(Pbuf + a2off((unsigned)((kt * 4 + it) * 64 + l)));
#pragma unroll
      for (int j = 0; j < 4; ++j) bfr[j] = B2p[(kt * 16 + w * 4 + j) * 64 + l];
#pragma unroll
      for (int it = 0; it < 4; ++it)
#pragma unroll
        for (int j = 0; j < 4; ++j)
          acc2[it][j] = __builtin_amdgcn_mfma_f32_16x16x32_f16(av[it], bfr[j], acc2[it][j], 0, 0, 0);
    }
  }

  // ---- store: 64 rows x 64 cols (cols w*64 + c*4 + j), float4 nt-stores ----
  const f32x4 b24 = *(const f32x4*)(pb2 + w * 64 + c * 4);
#pragma unroll
  for (int it = 0; it < 4; ++it)
#pragma unroll
    for (int r = 0; r < 4; ++r) {
      const int grow = rowbase + it * 16 + q * 4 + r;
      f32x4 st;
#pragma unroll
      for (int j = 0; j < 4; ++j) st[j] = acc2[it][j][r] + b24[j];
      __builtin_nontemporal_store(st, (f32x4*)(out + grow * 256 + w * 64 + c * 4));
    }
}

extern "C" void kernel_launch(void* const* d_in, const int* in_sizes, int n_in,
                              void* d_out, int out_size, void* d_ws, size_t ws_size,
                              hipStream_t stream) {
  (void)in_sizes; (void)n_in; (void)out_size; (void)ws_size;
  const float* f0 = (const float*)d_in[0];
  const int* phone = (const int*)d_in[1];
  const float* dur = (const float*)d_in[2];
  const int* midi = (const int*)d_in[3];
  const float* f0_w1 = (const float*)d_in[4];
  const float* f0_b1 = (const float*)d_in[5];
  const float* f0_w2 = (const float*)d_in[6];
  const float* f0_b2 = (const float*)d_in[7];
  const float* ptab = (const float*)d_in[8];
  const float* mtab = (const float*)d_in[9];
  const float* dur_w1 = (const float*)d_in[10];
  const float* dur_b1 = (const float*)d_in[11];
  const float* dur_w2 = (const float*)d_in[12];
  const float* dur_b2 = (const float*)d_in[13];
  const float* W1 = (const float*)d_in[14];
  const float* pb1 = (const float*)d_in[15];
  const float* ln_g = (const float*)d_in[16];
  const float* ln_b = (const float*)d_in[17];
  const float* W2 = (const float*)d_in[18];
  const float* pb2 = (const float*)d_in[19];
  char* ws = (char*)d_ws;
  float* out = (float*)d_out;

  prep_tables<<<293, 1024, 0, stream>>>(f0_w2, f0_b2, ptab, mtab, dur_w2, dur_b2, W1, pb1, (float*)ws);
  prep_frags<<<160, 64, 0, stream>>>(W2, ws);
  cond_enc_main<<<NBLK, 256, 0, stream>>>(f0, phone, dur, midi, f0_w1, f0_b1, dur_w1, dur_b1,
                                          ln_g, ln_b, pb2, ws, out);
}